// Round 8
// baseline (548.615 us; speedup 1.0000x reference)
//
#include <hip/hip_runtime.h>
#include <hip/hip_cooperative_groups.h>
#include <math.h>

namespace cg = cooperative_groups;

#define H 512
#define NN 8
#define NC 5
#define GRID 768

// ---------- math helpers (saturation-safe fast transcendentals) ----------
__device__ __forceinline__ float reluf(float x) { return x > 0.f ? x : 0.f; }

__device__ __forceinline__ float sigf(float x) {
    return 1.0f / (1.0f + __expf(-x));   // saturates cleanly, no NaN
}

__device__ __forceinline__ float tanh_fast(float x) {
    float ax = fabsf(x);
    float e = __expf(2.0f * ax);
    float t = 1.0f - 2.0f / (e + 1.0f);  // exp overflow -> exactly 1
    return copysignf(t, x);
}

// combine for one output column k; r1/r2 are the cell's [8][H] raw dots.
__device__ __forceinline__ float combine_fn(const float* __restrict__ r1,
                                            const float* __restrict__ r2,
                                            int k) {
    float t[8];
#pragma unroll
    for (int n = 0; n < 8; ++n)
        t[n] = reluf(r1[n * H + k]) + reluf(r2[n * H + k]);
    float m0 = reluf(t[0]) + sigf(t[3]);
    float m1 = sigf(t[1]) + tanh_fast(t[2]);
    float m2 = sigf(t[4]) * tanh_fast(t[5]);
    float m3 = sigf(t[6]) * reluf(t[7]);
    float m4 = sigf(m1) + tanh_fast(m2);
    float m5 = tanh_fast(m0) * tanh_fast(m3);
    float m6 = tanh_fast(m4) * tanh_fast(m5);
    return tanh_fast(m6);
}

struct Ptrs { const float* x[6]; };  // a,b,c,d,e,state_init

// One cooperative kernel: zero -> phaseA (48 matvecs) -> 4x phaseB -> final.
// 768 blocks = 3 blocks/CU co-resident (low VGPR, 128B LDS). 6 grid syncs.
__global__ __launch_bounds__(256) void k_fused(Ptrs P,
                                               const float* __restrict__ W1,
                                               const float* __restrict__ W2,
                                               float* __restrict__ raw1,
                                               float* __restrict__ raw2,
                                               float* __restrict__ out) {
    cg::grid_group grid = cg::this_grid();
    const int bid = blockIdx.x;
    const int t = threadIdx.x;
    __shared__ float sx[32];

    // ---- phase 0: zero the 2*[5][8][512] atomic accumulators (contiguous)
    {
        int idx = bid * 256 + t;
        if (idx < 2 * NC * NN * H) raw1[idx] = 0.f;
    }
    grid.sync();

    // ---- phase A: 40 x@W1 + cell-0 h@W2.  48 matrices x 16 chunks(32 rows)
    {
        int c = bid & 15;   // 32-row chunk
        int m = bid >> 4;   // matrix 0..47
        const float* x; const float* W; float* dst;
        if (m < 40) { x = P.x[m >> 3]; W = W1 + (size_t)m * H * H; dst = raw1 + m * H; }
        else { int n = m - 40; x = P.x[5]; W = W2 + (size_t)n * H * H; dst = raw2 + n * H; }
        if (t < 32) sx[t] = x[c * 32 + t];
        __syncthreads();
        int k0 = t * 2;
        const float* Wp = W + (size_t)(c * 32) * H + k0;
        float ax = 0.f, ay = 0.f;
#pragma unroll
        for (int h = 0; h < 32; ++h) {
            float2 w = *(const float2*)(Wp + (size_t)h * H);
            ax = fmaf(sx[h], w.x, ax);
            ay = fmaf(sx[h], w.y, ay);
        }
        atomicAdd(dst + k0, ax);
        atomicAdd(dst + k0 + 1, ay);
    }
    grid.sync();

    // ---- phase B: cells 1..4 sequential. 8 nodes x 32 chunks(16 rows) = 256 blocks
    for (int cell = 1; cell < NC; ++cell) {
        if (bid < 256) {
            int c = bid & 31;   // 16-row chunk
            int n = bid >> 5;   // node
            const float* r1p = raw1 + (size_t)(cell - 1) * NN * H;
            const float* r2p = raw2 + (size_t)(cell - 1) * NN * H;
            if (t < 16) sx[t] = combine_fn(r1p, r2p, c * 16 + t);
            __syncthreads();
            const float* W = W2 + (size_t)(cell * 8 + n) * H * H + (size_t)(c * 16) * H;
            int k0 = t * 2;
            float ax = 0.f, ay = 0.f;
#pragma unroll
            for (int h = 0; h < 16; ++h) {
                float2 w = *(const float2*)(W + (size_t)h * H + k0);
                ax = fmaf(sx[h], w.x, ax);
                ay = fmaf(sx[h], w.y, ay);
            }
            float* dst = raw2 + (size_t)(cell * NN + n) * H + k0;
            atomicAdd(dst, ax);
            atomicAdd(dst + 1, ay);
        }
        // NOTE: __syncthreads inside divergent 'if(bid<256)' is fine (whole
        // block takes same branch), but grid.sync must be hit by ALL blocks:
        grid.sync();
    }

    // ---- final combine -> out[512]
    if (bid < 2) {
        int k = bid * 256 + t;
        out[k] = combine_fn(raw1 + (size_t)4 * NN * H,
                            raw2 + (size_t)4 * NN * H, k);
    }
}

extern "C" void kernel_launch(void* const* d_in, const int* in_sizes, int n_in,
                              void* d_out, int out_size, void* d_ws, size_t ws_size,
                              hipStream_t stream) {
    const float* W1 = (const float*)d_in[6];
    const float* W2 = (const float*)d_in[7];
    float* out = (float*)d_out;

    float* ws = (float*)d_ws;
    float* raw1 = ws;                   // [5][8][512] pre-relu x@W1
    float* raw2 = ws + NC * NN * H;     // [5][8][512] pre-relu h@W2

    Ptrs P;
    P.x[0] = (const float*)d_in[0];
    P.x[1] = (const float*)d_in[1];
    P.x[2] = (const float*)d_in[2];
    P.x[3] = (const float*)d_in[3];
    P.x[4] = (const float*)d_in[4];
    P.x[5] = (const float*)d_in[5];

    void* args[] = { &P, &W1, &W2, &raw1, &raw2, &out };
    hipLaunchCooperativeKernel((const void*)k_fused, dim3(GRID), dim3(256),
                               args, 0, stream);
}

// Round 10
// 133.437 us; speedup vs baseline: 4.1114x; 4.1114x over previous
//
#include <hip/hip_runtime.h>
#include <math.h>

#define H 512
#define NN 8
#define NC 5

// ---------- math helpers (saturation-safe fast transcendentals) ----------
__device__ __forceinline__ float reluf(float x) { return x > 0.f ? x : 0.f; }

__device__ __forceinline__ float sigf(float x) {
    return 1.0f / (1.0f + __expf(-x));   // saturates cleanly, no NaN
}

__device__ __forceinline__ float tanh_fast(float x) {
    float ax = fabsf(x);
    float e = __expf(2.0f * ax);
    float t = 1.0f - 2.0f / (e + 1.0f);  // exp overflow -> exactly 1
    return copysignf(t, x);
}

// combine for one output column k; r1/r2 are the cell's [8][H] raw dots.
__device__ __forceinline__ float combine_fn(const float* __restrict__ r1,
                                            const float* __restrict__ r2,
                                            int k) {
    float t[8];
#pragma unroll
    for (int n = 0; n < 8; ++n)
        t[n] = reluf(r1[n * H + k]) + reluf(r2[n * H + k]);
    float m0 = reluf(t[0]) + sigf(t[3]);
    float m1 = sigf(t[1]) + tanh_fast(t[2]);
    float m2 = sigf(t[4]) * tanh_fast(t[5]);
    float m3 = sigf(t[6]) * reluf(t[7]);
    float m4 = sigf(m1) + tanh_fast(m2);
    float m5 = tanh_fast(m0) * tanh_fast(m3);
    float m6 = tanh_fast(m4) * tanh_fast(m5);
    return tanh_fast(m6);
}

struct Ptrs { const float* x[6]; };  // a,b,c,d,e,state_init

// raw layout (interleaved so cell-0 region is one contiguous memset):
//   raw[cell][2][8][512]; cell stride = 2*NN*H = 8192 floats.
//   side 0 = x@W1 raws, side 1 = h@W2 raws.

// ---- stage kernel: cell i = 16 matvecs (8x W1[i]@x_i, 8x W2[i]@h_{i-1}) --
// grid = 16 matrices * 32 chunks(16 rows) = 512 blocks (2/CU), 256 threads.
// W2-side blocks recompute h_{i-1} = combine(raw[i-1]) for their 16 rows
// (L2-hot, 16 loads/eval). Blocks 0..31 also zero cell i+1's raw region
// (visible to next dispatch via the dispatch boundary).
__global__ __launch_bounds__(256) void k_stage(int cell, Ptrs P,
                                               const float* __restrict__ W1,
                                               const float* __restrict__ W2,
                                               float* __restrict__ raw) {
    const int bid = blockIdx.x;
    const int t = threadIdx.x;
    const int c = bid & 31;   // 16-row chunk
    const int m = bid >> 5;   // matrix 0..15 (0..7 = W1 side, 8..15 = W2 side)

    float* base = raw + (size_t)cell * 2 * NN * H;

    __shared__ float sx[16];
    if (m < 8) {
        if (t < 16) sx[t] = P.x[cell][c * 16 + t];          // x_i
    } else if (cell == 0) {
        if (t < 16) sx[t] = P.x[5][c * 16 + t];             // state_init
    } else {
        const float* pb = raw + (size_t)(cell - 1) * 2 * NN * H;
        if (t < 16) sx[t] = combine_fn(pb, pb + NN * H, c * 16 + t);  // h_{i-1}
    }
    __syncthreads();

    const int node = m & 7;
    const float* W = (m < 8 ? W1 : W2) +
                     ((size_t)cell * NN + node) * H * H + (size_t)(c * 16) * H;
    const int k0 = t * 2;
    float ax = 0.f, ay = 0.f;
#pragma unroll
    for (int h = 0; h < 16; ++h) {
        float2 w = *(const float2*)(W + (size_t)h * H + k0);
        ax = fmaf(sx[h], w.x, ax);
        ay = fmaf(sx[h], w.y, ay);
    }
    float* dst = base + (m < 8 ? 0 : NN * H) + node * H + k0;
    atomicAdd(dst, ax);
    atomicAdd(dst + 1, ay);

    // zero next cell's accumulators (32 blocks * 256 threads = 8192 floats)
    if (cell < NC - 1 && bid < 32) {
        raw[(size_t)(cell + 1) * 2 * NN * H + bid * 256 + t] = 0.f;
    }
}

// ---------- final combine -> out[512] ------------------------------------
__global__ __launch_bounds__(256) void k_final(const float* __restrict__ raw,
                                               float* __restrict__ out) {
    int k = blockIdx.x * 256 + threadIdx.x;
    const float* base = raw + (size_t)(NC - 1) * 2 * NN * H;
    if (k < H) out[k] = combine_fn(base, base + NN * H, k);
}

extern "C" void kernel_launch(void* const* d_in, const int* in_sizes, int n_in,
                              void* d_out, int out_size, void* d_ws, size_t ws_size,
                              hipStream_t stream) {
    const float* W1 = (const float*)d_in[6];
    const float* W2 = (const float*)d_in[7];
    float* out = (float*)d_out;
    float* raw = (float*)d_ws;   // [5][2][8][512] f32

    Ptrs P;
    P.x[0] = (const float*)d_in[0];
    P.x[1] = (const float*)d_in[1];
    P.x[2] = (const float*)d_in[2];
    P.x[3] = (const float*)d_in[3];
    P.x[4] = (const float*)d_in[4];
    P.x[5] = (const float*)d_in[5];

    // zero cell-0 accumulators only (32 KB); stages zero their successor
    hipMemsetAsync(raw, 0, (size_t)2 * NN * H * sizeof(float), stream);

    for (int cell = 0; cell < NC; ++cell)
        k_stage<<<dim3(512), dim3(256), 0, stream>>>(cell, P, W1, W2, raw);
    k_final<<<dim3(2), dim3(256), 0, stream>>>(raw, out);
}

// Round 12
// 130.568 us; speedup vs baseline: 4.2018x; 1.0220x over previous
//
#include <hip/hip_runtime.h>
#include <math.h>

#define H 512
#define NN 8
#define NC 5

// ---------- math helpers (saturation-safe fast transcendentals) ----------
__device__ __forceinline__ float reluf(float x) { return x > 0.f ? x : 0.f; }

__device__ __forceinline__ float sigf(float x) {
    return 1.0f / (1.0f + __expf(-x));   // saturates cleanly, no NaN
}

__device__ __forceinline__ float tanh_fast(float x) {
    float ax = fabsf(x);
    float e = __expf(2.0f * ax);
    float t = 1.0f - 2.0f / (e + 1.0f);  // exp overflow -> exactly 1
    return copysignf(t, x);
}

// combine for one output column k; r1/r2 are the cell's [8][H] raw dots.
__device__ __forceinline__ float combine_fn(const float* __restrict__ r1,
                                            const float* __restrict__ r2,
                                            int k) {
    float t[8];
#pragma unroll
    for (int n = 0; n < 8; ++n)
        t[n] = reluf(r1[n * H + k]) + reluf(r2[n * H + k]);
    float m0 = reluf(t[0]) + sigf(t[3]);
    float m1 = sigf(t[1]) + tanh_fast(t[2]);
    float m2 = sigf(t[4]) * tanh_fast(t[5]);
    float m3 = sigf(t[6]) * reluf(t[7]);
    float m4 = sigf(m1) + tanh_fast(m2);
    float m5 = tanh_fast(m0) * tanh_fast(m3);
    float m6 = tanh_fast(m4) * tanh_fast(m5);
    return tanh_fast(m6);
}

struct Ptrs { const float* x[6]; };  // a,b,c,d,e,state_init

// raw layout: raw[cell][side][node][k]; side 0 = x@W1, side 1 = h@W2.
// cell stride = 2*NN*H = 8192 floats. No zeroing needed (direct stores).

// ---- stage kernel: cell i = 16 matvecs, atomic-free ---------------------
// grid = 16 matrices * 16 k-tiles(32 cols) = 256 blocks, 512 threads.
// Each block reduces the FULL 512-row dot for its 32 columns:
//   prefetch 8x float4 of W (indep of h) -> compute h into LDS (W2 side
//   recomputes previous cell's combine; L2-hot) -> FMA -> LDS tree-reduce
//   over 64 row-groups -> one float4 store per 4 cols. 128B row segments
//   (full L2 lines, no overfetch).
__global__ __launch_bounds__(512) void k_stage(int cell, Ptrs P,
                                               const float* __restrict__ W1,
                                               const float* __restrict__ W2,
                                               float* __restrict__ raw) {
    const int t   = threadIdx.x;
    const int bid = blockIdx.x;
    const int j    = bid & 15;   // k-tile (32 cols)
    const int m    = bid >> 4;   // 0..15
    const int node = m & 7;
    const int side = m >> 3;     // 0 = W1/x side, 1 = W2/h side

    const int cg = t & 7;        // float4 col-group within tile
    const int rg = t >> 3;       // row-group 0..63

    const float* Wsel = (side == 0 ? W1 : W2) +
                        (size_t)(cell * NN + node) * H * H;
    const float* Wp = Wsel + (size_t)rg * H + j * 32 + cg * 4;

    // prefetch all 8 W float4s (independent of h; latency hides under
    // the h/LDS phase below)
    float4 wv[8];
#pragma unroll
    for (int i = 0; i < 8; ++i)
        wv[i] = *(const float4*)(Wp + (size_t)(i * 64) * H);

    __shared__ float sh[H];
    if (side == 0) {
        sh[t] = P.x[cell][t];                    // x_i
    } else if (cell == 0) {
        sh[t] = P.x[5][t];                       // state_init
    } else {
        const float* pb = raw + (size_t)(cell - 1) * 2 * NN * H;
        sh[t] = combine_fn(pb, pb + NN * H, t);  // h_{i-1} (L2-hot)
    }
    __syncthreads();

    float4 acc = {0.f, 0.f, 0.f, 0.f};
#pragma unroll
    for (int i = 0; i < 8; ++i) {
        float s = sh[i * 64 + rg];               // 8-lane broadcast, no conflict
        acc.x = fmaf(s, wv[i].x, acc.x);
        acc.y = fmaf(s, wv[i].y, acc.y);
        acc.z = fmaf(s, wv[i].z, acc.z);
        acc.w = fmaf(s, wv[i].w, acc.w);
    }

    // tree-reduce over the 64 row-groups (pad 33 -> ~2-way conflicts, free)
    __shared__ float red[64][33];
    red[rg][cg * 4 + 0] = acc.x;
    red[rg][cg * 4 + 1] = acc.y;
    red[rg][cg * 4 + 2] = acc.z;
    red[rg][cg * 4 + 3] = acc.w;
    __syncthreads();
#pragma unroll
    for (int s = 32; s >= 1; s >>= 1) {
        if (rg < s) {
#pragma unroll
            for (int c2 = 0; c2 < 4; ++c2)
                red[rg][cg * 4 + c2] += red[rg + s][cg * 4 + c2];
        }
        __syncthreads();
    }
    if (rg == 0) {
        float* dst = raw + (size_t)cell * 2 * NN * H + (size_t)side * NN * H +
                     (size_t)node * H + j * 32 + cg * 4;
        dst[0] = red[0][cg * 4 + 0];
        dst[1] = red[0][cg * 4 + 1];
        dst[2] = red[0][cg * 4 + 2];
        dst[3] = red[0][cg * 4 + 3];
    }
}

// ---------- final combine -> out[512] ------------------------------------
__global__ __launch_bounds__(512) void k_final(const float* __restrict__ raw,
                                               float* __restrict__ out) {
    const int t = threadIdx.x;   // 1 block, 512 threads
    const float* base = raw + (size_t)(NC - 1) * 2 * NN * H;
    out[t] = combine_fn(base, base + NN * H, t);
}

extern "C" void kernel_launch(void* const* d_in, const int* in_sizes, int n_in,
                              void* d_out, int out_size, void* d_ws, size_t ws_size,
                              hipStream_t stream) {
    const float* W1 = (const float*)d_in[6];
    const float* W2 = (const float*)d_in[7];
    float* out = (float*)d_out;
    float* raw = (float*)d_ws;   // [5][2][8][512] f32, no zeroing needed

    Ptrs P;
    P.x[0] = (const float*)d_in[0];
    P.x[1] = (const float*)d_in[1];
    P.x[2] = (const float*)d_in[2];
    P.x[3] = (const float*)d_in[3];
    P.x[4] = (const float*)d_in[4];
    P.x[5] = (const float*)d_in[5];

    for (int cell = 0; cell < NC; ++cell)
        k_stage<<<dim3(256), dim3(512), 0, stream>>>(cell, P, W1, W2, raw);
    k_final<<<dim3(1), dim3(512), 0, stream>>>(raw, out);
}